// Round 14
// baseline (48.802 us; speedup 1.0000x reference)
//
#include <hip/hip_runtime.h>

// Problem constants: B=4, N=512, M=512, D=128, H=256, DOUT=128
#define BB    4
#define NN    512
#define MM    512
#define DD    128
#define HH    256
#define DOUTC 128

typedef float v4f __attribute__((ext_vector_type(4)));

// ---------------------------------------------------------------------------
// Kernel 1: precompute (256 blocks x 1024 threads) — VERIFIED round-13 version.
//   AT[b][h][m] = Y[b,m]·W1[0:D,h]   ;   CT[b][h][n] = X[b,n]·W1[D:2D,h]+b1[h]
// ---------------------------------------------------------------------------
__global__ __launch_bounds__(1024) void precompute_ac(
    const float* __restrict__ X, const float* __restrict__ Y,
    const float* __restrict__ W1, const float* __restrict__ b1,
    float* __restrict__ AT, float* __restrict__ CT)
{
    __shared__ __align__(16) float rows[16][DD];     // 8 KB
    __shared__ __align__(16) v4f mrg[3][4][4][64];   // 48 KB: [dq-1][rs][r][hq]
    const int bid = blockIdx.x;
    const int t   = threadIdx.x;
    const int isC = bid >> 7;
    const int r0  = (bid & 127) * 16;                // global row (b*512+m)
    const float* src = isC ? X : Y;

    if (t < 512)
        reinterpret_cast<v4f*>(&rows[0][0])[t] =
            reinterpret_cast<const v4f*>(src + (size_t)r0 * DD)[t];
    __syncthreads();

    const int hq = t & 63;            // h-quad
    const int dq = (t >> 6) & 3;      // d-chunk (wave-uniform)
    const int rs = t >> 8;            // row-group (wave-uniform)
    const int d0 = dq * 32;
    const float* wp = W1 + (isC ? DD * HH : 0) + hq * 4;

    v4f acc[4];
#pragma unroll
    for (int r = 0; r < 4; ++r) acc[r] = (v4f){0.f, 0.f, 0.f, 0.f};

#pragma unroll 2
    for (int dg = 0; dg < 32; dg += 4) {
        const int d = d0 + dg;
        const v4f w0 = *reinterpret_cast<const v4f*>(&wp[(d + 0) * HH]);
        const v4f w1 = *reinterpret_cast<const v4f*>(&wp[(d + 1) * HH]);
        const v4f w2 = *reinterpret_cast<const v4f*>(&wp[(d + 2) * HH]);
        const v4f w3 = *reinterpret_cast<const v4f*>(&wp[(d + 3) * HH]);
#pragma unroll
        for (int r = 0; r < 4; ++r) {
            const v4f rv = *reinterpret_cast<const v4f*>(&rows[rs * 4 + r][d]);
            acc[r] += w0 * rv.x;
            acc[r] += w1 * rv.y;
            acc[r] += w2 * rv.z;
            acc[r] += w3 * rv.w;
        }
    }

    if (dq > 0) {
#pragma unroll
        for (int r = 0; r < 4; ++r) mrg[dq - 1][rs][r][hq] = acc[r];
    }
    __syncthreads();
    if (dq == 0) {
#pragma unroll
        for (int r = 0; r < 4; ++r) {
#pragma unroll
            for (int p = 0; p < 3; ++p) acc[r] += mrg[p][rs][r][hq];
        }
        v4f bias = (v4f){0.f, 0.f, 0.f, 0.f};
        if (isC) bias = *reinterpret_cast<const v4f*>(&b1[hq * 4]);
#pragma unroll
        for (int r = 0; r < 4; ++r) acc[r] += bias;

        // transposed store: 4 consecutive m per h column
        const int grow = r0 + rs * 4;
        const int bb   = grow >> 9;
        const int mm   = grow & 511;
        float* Tb = isC ? CT : AT;
#pragma unroll
        for (int u = 0; u < 4; ++u) {
            const v4f w = (v4f){acc[0][u], acc[1][u], acc[2][u], acc[3][u]};
            *reinterpret_cast<v4f*>(
                &Tb[((size_t)(bb * HH + hq * 4 + u)) * 512 + mm]) = w;
        }
    }
}

// ---------------------------------------------------------------------------
// Kernel 2: WAVE-SYNCHRONOUS sort + query (256 blocks x 256 threads).
// One column (b,h) per wave; ZERO __syncthreads (round-13 was barrier-bound:
// 54 block-wide barrier stages at 1 block/CU = ~33 us).
// 512 elems in 8 regs/lane, e = r*64 + l. Bitonic: j>=64 stages = register
// swaps; j<64 stages = shfl_xor compare-exchange. Prefix: lane-local + shfl_up
// wave scan. LDS is wave-private staging for the binary-search gather, ordered
// by s_waitcnt lgkmcnt(0) + sched_barrier (wave-sync idiom).
//   S[n,h] = (T - P_k) + (512-k)*c,  k = #{a_m < -c}   (exact relu-sum)
// ---------------------------------------------------------------------------
__global__ __launch_bounds__(256) void sort_query(
    const float* __restrict__ AT, const float* __restrict__ CT,
    float* __restrict__ ST)
{
    __shared__ float vals[4][512];   // sorted values, wave-private slice
    __shared__ float pref[4][512];   // inclusive prefix
    const int wid = threadIdx.x >> 6;
    const int l   = threadIdx.x & 63;
    const int col = blockIdx.x * 4 + wid;    // 0..1023 = b*256 + h

    // load column (coalesced)
    float a[8];
    const float* Ac = AT + (size_t)col * 512;
#pragma unroll
    for (int r = 0; r < 8; ++r) a[r] = Ac[r * 64 + l];

    // ---- bitonic sort ascending over e = r*64 + l ----
    for (int k = 2; k <= 512; k <<= 1) {
        for (int j = k >> 1; j > 0; j >>= 1) {
            if (j >= 64) {
                const int rj = j >> 6;      // 1, 2 or 4
#pragma unroll
                for (int r = 0; r < 8; ++r) {
                    if ((r & rj) == 0) {
                        const int rh = r | rj;
                        const bool asc = (((r << 6) & k) == 0);
                        const float x = a[r], y = a[rh];
                        const float mn = fminf(x, y), mx = fmaxf(x, y);
                        a[r]  = asc ? mn : mx;
                        a[rh] = asc ? mx : mn;
                    }
                }
            } else {
                const bool lower = ((l & j) == 0);
#pragma unroll
                for (int r = 0; r < 8; ++r) {
                    const bool asc = (k >= 64) ? (((r << 6) & k) == 0)
                                               : ((l & k) == 0);
                    const float other = __shfl_xor(a[r], j, 64);
                    const bool take_min = (lower == asc);
                    const float mn = fminf(a[r], other);
                    const float mx = fmaxf(a[r], other);
                    a[r] = take_min ? mn : mx;
                }
            }
        }
    }

    // ---- stage sorted array to LDS (wave-private; wave-sync ordering) ----
#pragma unroll
    for (int r = 0; r < 8; ++r) vals[wid][r * 64 + l] = a[r];
    asm volatile("s_waitcnt lgkmcnt(0)" ::: "memory");
    __builtin_amdgcn_sched_barrier(0);

    // ---- prefix sum: chunk-local + shfl_up wave scan ----
    float v[8], p[8];
#pragma unroll
    for (int q = 0; q < 8; ++q) v[q] = vals[wid][l * 8 + q];
    p[0] = v[0];
#pragma unroll
    for (int q = 1; q < 8; ++q) p[q] = p[q - 1] + v[q];
    float run = p[7];
#pragma unroll
    for (int off = 1; off < 64; off <<= 1) {
        const float tv = __shfl_up(run, off, 64);
        if (l >= off) run += tv;
    }
    const float Ttot = __shfl(run, 63, 64);
    const float excl = run - p[7];
#pragma unroll
    for (int q = 0; q < 8; ++q) pref[wid][l * 8 + q] = p[q] + excl;
    asm volatile("s_waitcnt lgkmcnt(0)" ::: "memory");
    __builtin_amdgcn_sched_barrier(0);

    // ---- queries: n = q*64 + l (coalesced CT read / ST write) ----
    const float* Cc = CT + (size_t)col * 512;
    float* Sc       = ST + (size_t)col * 512;
#pragma unroll 2
    for (int q = 0; q < 8; ++q) {
        const int n = q * 64 + l;
        const float c = Cc[n];
        const float negc = -c;
        int kk = 0;
#pragma unroll
        for (int step = 512; step > 0; step >>= 1) {
            const int nk = kk + step;
            if (nk <= 512 && vals[wid][nk - 1] < negc) kk = nk;
        }
        const float Pk = (kk > 0) ? pref[wid][kk - 1] : 0.f;
        Sc[n] = (Ttot - Pk) + (float)(512 - kk) * c;
    }
}

// ---------------------------------------------------------------------------
// Kernel 3: epilogue GEMM (512 blocks x 512 threads, 4 bn-rows/block) —
// round-13 verified body; only the Sl staging reads transposed ST.
//   out[bn,o] = sum_h S[bn,h]*W2[h,o] + 512*b2[o]
// ---------------------------------------------------------------------------
__global__ __launch_bounds__(512) void epilogue(
    const float* __restrict__ ST, const float* __restrict__ W2,
    const float* __restrict__ b2, float* __restrict__ out)
{
    __shared__ __align__(16) float Sl[4][HH];   // 4 KB
    __shared__ __align__(16) v4f red[3 * 128];  // 6 KB
    const int bn0 = blockIdx.x * 4;
    const int b   = bn0 >> 9;
    const int n0l = bn0 & 511;
    const int t   = threadIdx.x;

    if (t < 256) {
#pragma unroll
        for (int r = 0; r < 4; ++r)
            Sl[r][t] = ST[((size_t)(b * HH + t)) * 512 + n0l + r];
    }
    __syncthreads();

    const int o0 = (t & 31) * 4;       // 128 o
    const int r  = (t >> 5) & 3;       // 4 rows
    const int kq = t >> 7;             // 4 k-quarters of 64
    const int k0 = kq * 64;
    v4f a4 = (v4f){0.f, 0.f, 0.f, 0.f};
    const float* w2p = W2 + o0;
#pragma unroll 4
    for (int k = k0; k < k0 + 64; k += 4) {
        const v4f sv = *reinterpret_cast<const v4f*>(&Sl[r][k]);  // broadcast
        const v4f wA = *reinterpret_cast<const v4f*>(&w2p[(k + 0) * DOUTC]);
        const v4f wB = *reinterpret_cast<const v4f*>(&w2p[(k + 1) * DOUTC]);
        const v4f wC = *reinterpret_cast<const v4f*>(&w2p[(k + 2) * DOUTC]);
        const v4f wD = *reinterpret_cast<const v4f*>(&w2p[(k + 3) * DOUTC]);
        a4 += wA * sv.x;
        a4 += wB * sv.y;
        a4 += wC * sv.z;
        a4 += wD * sv.w;
    }
    if (kq) red[(kq - 1) * 128 + (t & 127)] = a4;
    __syncthreads();
    if (kq == 0) {
#pragma unroll
        for (int p = 0; p < 3; ++p) a4 += red[p * 128 + (t & 127)];
        a4 += 512.f * (*reinterpret_cast<const v4f*>(&b2[o0]));
        *reinterpret_cast<v4f*>(&out[(size_t)(bn0 + r) * DOUTC + o0]) = a4;
    }
}

// ---------------------------------------------------------------------------
extern "C" void kernel_launch(void* const* d_in, const int* in_sizes, int n_in,
                              void* d_out, int out_size, void* d_ws, size_t ws_size,
                              hipStream_t stream) {
    const float* X  = (const float*)d_in[0];
    const float* Y  = (const float*)d_in[1];
    const float* W1 = (const float*)d_in[2];
    const float* b1 = (const float*)d_in[3];
    const float* W2 = (const float*)d_in[4];
    const float* b2 = (const float*)d_in[5];
    float* out = (float*)d_out;

    float* AT = (float*)d_ws;                    // [4][256][512] = 2 MB
    float* CT = AT + (size_t)BB * HH * 512;      // [4][256][512] = 2 MB
    float* ST = CT + (size_t)BB * HH * 512;      // [4][256][512] = 2 MB (transposed S)

    hipLaunchKernelGGL(precompute_ac, dim3(256), dim3(1024), 0, stream,
                       X, Y, W1, b1, AT, CT);
    hipLaunchKernelGGL(sort_query, dim3(256), dim3(256), 0, stream,
                       AT, CT, ST);
    hipLaunchKernelGGL(epilogue, dim3(BB * NN / 4), dim3(512), 0, stream,
                       ST, W2, b2, out);
}